// Round 1
// baseline (334.305 us; speedup 1.0000x reference)
//
#include <hip/hip_runtime.h>

#define SLEN 4096
#define DMODEL 768
#define NH 12
#define HD 64
#define NQKV 2304
#define KDIM 768

typedef _Float16 f16x8 __attribute__((ext_vector_type(8)));
typedef float f32x4 __attribute__((ext_vector_type(4)));

__device__ __forceinline__ void async16(void* lds, const void* g) {
  __builtin_amdgcn_global_load_lds((const __attribute__((address_space(1))) void*)g,
                                   (__attribute__((address_space(3))) void*)lds, 16, 0, 0);
}

__device__ __forceinline__ float fexp2(float x) { return __builtin_amdgcn_exp2f(x); }

// ---------------- pack / convert ----------------
__global__ __launch_bounds__(256) void pack_kernel(
    const float* __restrict__ x, const float* __restrict__ Wq, const float* __restrict__ Wk,
    const float* __restrict__ Wv, const float* __restrict__ Wo,
    _Float16* __restrict__ xb, _Float16* __restrict__ wqkvt, _Float16* __restrict__ wot) {
  int tid = blockIdx.x * 256 + threadIdx.x;
  int stride = gridDim.x * 256;
  for (int i = tid; i < SLEN * DMODEL; i += stride) xb[i] = (_Float16)x[i];
  // wqkvt[col][d], col = which*768 + h*64 + e
  for (int i = tid; i < NQKV * DMODEL; i += stride) {
    int col = i / DMODEL, d = i - col * DMODEL;
    int which = col / DMODEL;
    int cc = col - which * DMODEL;
    int h = cc >> 6, e = cc & 63;
    const float* W = which == 0 ? Wq : (which == 1 ? Wk : Wv);
    wqkvt[i] = (_Float16)W[(h * DMODEL + d) * HD + e];
  }
  // wot[o][d] = Wo[d][o]
  for (int i = tid; i < DMODEL * DMODEL; i += stride) {
    int e = i / DMODEL, d = i - e * DMODEL;
    wot[i] = (_Float16)Wo[d * DMODEL + e];
  }
}

// ---------------- shared GEMM core: C[128,128] = A[128xK] * Bt[128xK]^T ----------------
__device__ __forceinline__ void gemm_core(const _Float16* __restrict__ A,
                                          const _Float16* __restrict__ Bt,
                                          _Float16* As, _Float16* Bs,
                                          f32x4 (&acc)[4][4], int m0, int n0) {
  int t = threadIdx.x;
  int lane = t & 63, w = t >> 6;
  int lr = lane & 15, lg = lane >> 4;
  int wr = w >> 1, wc = w & 1;
  for (int kb = 0; kb < KDIM / 64; ++kb) {
    #pragma unroll
    for (int i = 0; i < 4; ++i) {
      int base = (w * 4 + i) * 512;      // f16 elements
      int off = base + lane * 8;
      int row = off >> 6, col = off & 63;
      async16(&As[base], A + (m0 + row) * KDIM + kb * 64 + col);
      async16(&Bs[base], Bt + (n0 + row) * KDIM + kb * 64 + col);
    }
    __syncthreads();
    #pragma unroll
    for (int kk = 0; kk < 2; ++kk) {
      f16x8 af[4], bf[4];
      #pragma unroll
      for (int mi = 0; mi < 4; ++mi)
        af[mi] = *(const f16x8*)&As[(wr * 64 + mi * 16 + lr) * 64 + kk * 32 + lg * 8];
      #pragma unroll
      for (int ni = 0; ni < 4; ++ni)
        bf[ni] = *(const f16x8*)&Bs[(wc * 64 + ni * 16 + lr) * 64 + kk * 32 + lg * 8];
      #pragma unroll
      for (int mi = 0; mi < 4; ++mi)
        #pragma unroll
        for (int ni = 0; ni < 4; ++ni)
          acc[mi][ni] = __builtin_amdgcn_mfma_f32_16x16x32_f16(af[mi], bf[ni], acc[mi][ni], 0, 0, 0);
    }
    __syncthreads();
  }
}

// ---------------- QKV projection GEMM ----------------
__global__ __launch_bounds__(256) void gemm_qkv(
    const _Float16* __restrict__ xb, const _Float16* __restrict__ wqkvt,
    const float* __restrict__ bq, const float* __restrict__ bk, const float* __restrict__ bv,
    _Float16* __restrict__ qd, _Float16* __restrict__ kd, _Float16* __restrict__ vtd) {
  __shared__ __align__(16) _Float16 As[128 * 64];
  __shared__ __align__(16) _Float16 Bs[128 * 64];
  f32x4 acc[4][4] = {};
  int m0 = blockIdx.y * 128, n0 = blockIdx.x * 128;
  gemm_core(xb, wqkvt, As, Bs, acc, m0, n0);
  int t = threadIdx.x, lane = t & 63, w = t >> 6;
  int lr = lane & 15, lg = lane >> 4;
  int wr = w >> 1, wc = w & 1;
  int which = n0 / DMODEL;  // 768 = 6*128, so 'which' is block-uniform
  const float* bias = which == 0 ? bq : (which == 1 ? bk : bv);
  #pragma unroll
  for (int mi = 0; mi < 4; ++mi)
    #pragma unroll
    for (int ni = 0; ni < 4; ++ni)
      #pragma unroll
      for (int r = 0; r < 4; ++r) {
        int srow = m0 + wr * 64 + mi * 16 + lg * 4 + r;
        int col = n0 + wc * 64 + ni * 16 + lr;
        int cc = col - which * DMODEL;
        int h = cc >> 6, e = cc & 63;
        float val = acc[mi][ni][r] + bias[cc];
        if (which < 2) {
          (which ? kd : qd)[h * (SLEN * HD) + srow * HD + e] = (_Float16)val;
        } else {
          vtd[h * (SLEN * HD) + e * SLEN + srow] = (_Float16)val;  // V transposed per head
        }
      }
}

// ---------------- flash attention: block = (64 q-rows, head) ----------------
__global__ __launch_bounds__(256) void attn_kernel(
    const _Float16* __restrict__ qd, const _Float16* __restrict__ kd,
    const _Float16* __restrict__ vtd, _Float16* __restrict__ attn) {
  __shared__ __align__(16) _Float16 Qs[64 * 64];
  __shared__ __align__(16) _Float16 Ks[64 * 64];
  __shared__ __align__(16) _Float16 Vts[64 * 64];
  __shared__ __align__(16) _Float16 Pb[4 * 16 * 64];
  int qb = blockIdx.x, h = blockIdx.y;
  int t = threadIdx.x, lane = t & 63, w = t >> 6;
  int lr = lane & 15, lg = lane >> 4;

  const _Float16* qbase = qd + h * (SLEN * HD) + qb * 64 * HD;
  #pragma unroll
  for (int i = 0; i < 2; ++i) {
    int base = (w * 2 + i) * 512;
    async16(&Qs[base], qbase + base + lane * 8);
  }
  __syncthreads();
  f16x8 qf[2];
  #pragma unroll
  for (int kk = 0; kk < 2; ++kk)
    qf[kk] = *(const f16x8*)&Qs[(w * 16 + lr) * 64 + kk * 32 + lg * 8];

  float mrow[4], lrow[4];
  f32x4 oacc[4];
  #pragma unroll
  for (int r = 0; r < 4; ++r) { mrow[r] = -1e30f; lrow[r] = 0.f; }
  #pragma unroll
  for (int ne = 0; ne < 4; ++ne) oacc[ne] = (f32x4){0.f, 0.f, 0.f, 0.f};

  const _Float16* kb_base = kd + h * (SLEN * HD);
  const _Float16* vb_base = vtd + h * (SLEN * HD);
  const float SCL = 0.125f * 1.44269504088896f;  // 1/sqrt(64) * log2(e)

  for (int jb = 0; jb < SLEN / 64; ++jb) {
    #pragma unroll
    for (int i = 0; i < 2; ++i) {
      int base = (w * 2 + i) * 512;
      int off = base + lane * 8;
      async16(&Ks[base], kb_base + jb * 4096 + off);
      async16(&Vts[base], vb_base + (off >> 6) * SLEN + jb * 64 + (off & 63));
    }
    __syncthreads();

    // S = Q * K^T  (A = Q rows, B-fragment reads K rows contiguously)
    f32x4 sacc[4];
    #pragma unroll
    for (int nj = 0; nj < 4; ++nj) sacc[nj] = (f32x4){0.f, 0.f, 0.f, 0.f};
    #pragma unroll
    for (int kk = 0; kk < 2; ++kk) {
      #pragma unroll
      for (int nj = 0; nj < 4; ++nj) {
        f16x8 kf = *(const f16x8*)&Ks[(nj * 16 + lr) * 64 + kk * 32 + lg * 8];
        sacc[nj] = __builtin_amdgcn_mfma_f32_16x16x32_f16(qf[kk], kf, sacc[nj], 0, 0, 0);
      }
    }

    // online softmax (rows = lg*4+r, cols = nj*16+lr), reduce across 16-lane group
    #pragma unroll
    for (int r = 0; r < 4; ++r) {
      float mb = fmaxf(fmaxf(sacc[0][r], sacc[1][r]), fmaxf(sacc[2][r], sacc[3][r])) * SCL;
      #pragma unroll
      for (int d = 1; d < 16; d <<= 1) mb = fmaxf(mb, __shfl_xor(mb, d, 64));
      float mn = fmaxf(mrow[r], mb);
      float corr = fexp2(mrow[r] - mn);
      mrow[r] = mn;
      float ps = 0.f;
      #pragma unroll
      for (int nj = 0; nj < 4; ++nj) {
        float p = fexp2(sacc[nj][r] * SCL - mn);
        sacc[nj][r] = p;
        ps += p;
      }
      lrow[r] = lrow[r] * corr + ps;
      #pragma unroll
      for (int ne = 0; ne < 4; ++ne) oacc[ne][r] *= corr;
      int row = lg * 4 + r;
      #pragma unroll
      for (int nj = 0; nj < 4; ++nj) {
        int col = nj * 16 + lr;
        int byteoff = (w * 2048 + row * 128 + col * 2) ^ ((row & 7) << 4);
        *(_Float16*)((char*)Pb + byteoff) = (_Float16)sacc[nj][r];
      }
    }

    // O += P * V   (A = P from swizzled LDS, B-fragment reads Vt rows contiguously)
    #pragma unroll
    for (int kk = 0; kk < 2; ++kk) {
      int aoff = (w * 2048 + lr * 128 + (kk * 32 + lg * 8) * 2) ^ ((lr & 7) << 4);
      f16x8 pf = *(const f16x8*)((char*)Pb + aoff);
      #pragma unroll
      for (int ne = 0; ne < 4; ++ne) {
        f16x8 vf = *(const f16x8*)&Vts[(ne * 16 + lr) * 64 + kk * 32 + lg * 8];
        oacc[ne] = __builtin_amdgcn_mfma_f32_16x16x32_f16(pf, vf, oacc[ne], 0, 0, 0);
      }
    }
    __syncthreads();
  }

  // epilogue: divide by row sum, write concat-head layout [s][h*64+e]
  #pragma unroll
  for (int r = 0; r < 4; ++r) {
    float ls = lrow[r];
    #pragma unroll
    for (int d = 1; d < 16; d <<= 1) ls += __shfl_xor(ls, d, 64);
    float inv = 1.f / ls;
    int srow = qb * 64 + w * 16 + lg * 4 + r;
    #pragma unroll
    for (int ne = 0; ne < 4; ++ne)
      attn[srow * DMODEL + h * HD + ne * 16 + lr] = (_Float16)(oacc[ne][r] * inv);
  }
}

// ---------------- output projection GEMM ----------------
__global__ __launch_bounds__(256) void gemm_out(
    const _Float16* __restrict__ attn, const _Float16* __restrict__ wot,
    const float* __restrict__ bo, float* __restrict__ out) {
  __shared__ __align__(16) _Float16 As[128 * 64];
  __shared__ __align__(16) _Float16 Bs[128 * 64];
  f32x4 acc[4][4] = {};
  int m0 = blockIdx.y * 128, n0 = blockIdx.x * 128;
  gemm_core(attn, wot, As, Bs, acc, m0, n0);
  int t = threadIdx.x, lane = t & 63, w = t >> 6;
  int lr = lane & 15, lg = lane >> 4;
  int wr = w >> 1, wc = w & 1;
  #pragma unroll
  for (int mi = 0; mi < 4; ++mi)
    #pragma unroll
    for (int ni = 0; ni < 4; ++ni)
      #pragma unroll
      for (int r = 0; r < 4; ++r) {
        int srow = m0 + wr * 64 + mi * 16 + lg * 4 + r;
        int col = n0 + wc * 64 + ni * 16 + lr;
        out[srow * DMODEL + col] = acc[mi][ni][r] + bo[col];
      }
}

extern "C" void kernel_launch(void* const* d_in, const int* in_sizes, int n_in,
                              void* d_out, int out_size, void* d_ws, size_t ws_size,
                              hipStream_t stream) {
  const float* x  = (const float*)d_in[0];
  const float* Wq = (const float*)d_in[1];
  const float* Wk = (const float*)d_in[2];
  const float* Wv = (const float*)d_in[3];
  const float* bq = (const float*)d_in[4];
  const float* bk = (const float*)d_in[5];
  const float* bv = (const float*)d_in[6];
  const float* Wo = (const float*)d_in[7];
  const float* bo = (const float*)d_in[8];
  float* out = (float*)d_out;

  char* ws = (char*)d_ws;
  size_t off = 0;
  auto alloc = [&](size_t bytes) {
    char* p = ws + off;
    off += (bytes + 255) & ~size_t(255);
    return p;
  };
  _Float16* xb    = (_Float16*)alloc((size_t)SLEN * DMODEL * 2);
  _Float16* wqkvt = (_Float16*)alloc((size_t)NQKV * DMODEL * 2);
  _Float16* wot   = (_Float16*)alloc((size_t)DMODEL * DMODEL * 2);
  _Float16* qd    = (_Float16*)alloc((size_t)NH * SLEN * HD * 2);
  _Float16* kd    = (_Float16*)alloc((size_t)NH * SLEN * HD * 2);
  _Float16* vtd   = (_Float16*)alloc((size_t)NH * SLEN * HD * 2);
  _Float16* attn  = (_Float16*)alloc((size_t)SLEN * DMODEL * 2);

  hipLaunchKernelGGL(pack_kernel, dim3(1024), dim3(256), 0, stream,
                     x, Wq, Wk, Wv, Wo, xb, wqkvt, wot);
  hipLaunchKernelGGL(gemm_qkv, dim3(NQKV / 128, SLEN / 128), dim3(256), 0, stream,
                     xb, wqkvt, bq, bk, bv, qd, kd, vtd);
  hipLaunchKernelGGL(attn_kernel, dim3(SLEN / 64, NH), dim3(256), 0, stream,
                     qd, kd, vtd, attn);
  hipLaunchKernelGGL(gemm_out, dim3(DMODEL / 128, SLEN / 128), dim3(256), 0, stream,
                     attn, wot, bo, out);
}

// Round 5
// 269.956 us; speedup vs baseline: 1.2384x; 1.2384x over previous
//
#include <hip/hip_runtime.h>

#define SLEN 4096
#define DMODEL 768
#define NH 12
#define HD 64
#define NQKV 2304
#define KDIM 768
#define KVBLK 64
#define NT (SLEN / KVBLK)

typedef _Float16 f16x8 __attribute__((ext_vector_type(8)));
typedef _Float16 f16x4v __attribute__((ext_vector_type(4)));
typedef float f32x4 __attribute__((ext_vector_type(4)));
typedef float f32x16 __attribute__((ext_vector_type(16)));

__device__ __forceinline__ void async16(void* lds, const void* g) {
  __builtin_amdgcn_global_load_lds((const __attribute__((address_space(1))) void*)g,
                                   (__attribute__((address_space(3))) void*)lds, 16, 0, 0);
}

// permlane32_swap via builtin (SSA-safe: no reg-aliasing hazard when a==b).
// new_a = [a.lo(0..31) | b.lo], new_b = [a.hi | b.hi(32..63)]
__device__ __forceinline__ void plswap(unsigned& a, unsigned& b) {
  auto r = __builtin_amdgcn_permlane32_swap(a, b, false, false);
  a = r[0];
  b = r[1];
}

__device__ __forceinline__ unsigned pk(float a, float b) {
  auto r = __builtin_amdgcn_cvt_pkrtz(a, b);   // __fp16 ext_vector_type(2)
  return __builtin_bit_cast(unsigned, r);
}

// ---------------- pack / convert (vectorized) ----------------
__global__ __launch_bounds__(256) void pack_kernel(
    const float* __restrict__ x, const float* __restrict__ Wq, const float* __restrict__ Wk,
    const float* __restrict__ Wv, const float* __restrict__ Wo,
    _Float16* __restrict__ xb, _Float16* __restrict__ wqkvt, _Float16* __restrict__ wot) {
  int tid = blockIdx.x * 256 + threadIdx.x;
  int stride = gridDim.x * 256;
  int n4 = SLEN * DMODEL / 4;
  for (int i = tid; i < n4; i += stride) {
    float4 v = ((const float4*)x)[i];
    f16x4v o = {(_Float16)v.x, (_Float16)v.y, (_Float16)v.z, (_Float16)v.w};
    ((f16x4v*)xb)[i] = o;
  }
  // wqkvt[col][d], col = which*768 + h*64 + e ; source stride HD floats along d
  n4 = NQKV * DMODEL / 4;
  for (int i = tid; i < n4; i += stride) {
    int col = i / (DMODEL / 4);
    int d = (i - col * (DMODEL / 4)) * 4;
    int which = col / DMODEL;
    int cc = col - which * DMODEL;
    int h = cc >> 6, e = cc & 63;
    const float* W = which == 0 ? Wq : (which == 1 ? Wk : Wv);
    const float* s = W + (h * DMODEL + d) * HD + e;
    f16x4v o = {(_Float16)s[0], (_Float16)s[HD], (_Float16)s[2 * HD], (_Float16)s[3 * HD]};
    ((f16x4v*)wqkvt)[i] = o;
  }
  // wot[o][d] = Wo[d*768+o]
  n4 = DMODEL * DMODEL / 4;
  for (int i = tid; i < n4; i += stride) {
    int o_ = i / (DMODEL / 4);
    int d = (i - o_ * (DMODEL / 4)) * 4;
    const float* s = Wo + d * DMODEL + o_;
    f16x4v o = {(_Float16)s[0], (_Float16)s[DMODEL], (_Float16)s[2 * DMODEL], (_Float16)s[3 * DMODEL]};
    ((f16x4v*)wot)[i] = o;
  }
}

// ---------------- shared GEMM core: C[128,128] = A[128xK] * Bt[128xK]^T ----------------
__device__ __forceinline__ void gemm_core(const _Float16* __restrict__ A,
                                          const _Float16* __restrict__ Bt,
                                          _Float16* As, _Float16* Bs,
                                          f32x4 (&acc)[4][4], int m0, int n0) {
  int t = threadIdx.x;
  int lane = t & 63, w = t >> 6;
  int lr = lane & 15, lg = lane >> 4;
  int wr = w >> 1, wc = w & 1;
  for (int kb = 0; kb < KDIM / 64; ++kb) {
    #pragma unroll
    for (int i = 0; i < 4; ++i) {
      int base = (w * 4 + i) * 512;
      int off = base + lane * 8;
      int row = off >> 6, col = off & 63;
      async16(&As[base], A + (m0 + row) * KDIM + kb * 64 + col);
      async16(&Bs[base], Bt + (n0 + row) * KDIM + kb * 64 + col);
    }
    __syncthreads();
    #pragma unroll
    for (int kk = 0; kk < 2; ++kk) {
      f16x8 af[4], bf[4];
      #pragma unroll
      for (int mi = 0; mi < 4; ++mi)
        af[mi] = *(const f16x8*)&As[(wr * 64 + mi * 16 + lr) * 64 + kk * 32 + lg * 8];
      #pragma unroll
      for (int ni = 0; ni < 4; ++ni)
        bf[ni] = *(const f16x8*)&Bs[(wc * 64 + ni * 16 + lr) * 64 + kk * 32 + lg * 8];
      #pragma unroll
      for (int mi = 0; mi < 4; ++mi)
        #pragma unroll
        for (int ni = 0; ni < 4; ++ni)
          acc[mi][ni] = __builtin_amdgcn_mfma_f32_16x16x32_f16(af[mi], bf[ni], acc[mi][ni], 0, 0, 0);
    }
    __syncthreads();
  }
}

// ---------------- QKV projection GEMM ----------------
__global__ __launch_bounds__(256) void gemm_qkv(
    const _Float16* __restrict__ xb, const _Float16* __restrict__ wqkvt,
    const float* __restrict__ bq, const float* __restrict__ bk, const float* __restrict__ bv,
    _Float16* __restrict__ qd, _Float16* __restrict__ kd, _Float16* __restrict__ vtd) {
  __shared__ __align__(16) _Float16 As[128 * 64];
  __shared__ __align__(16) _Float16 Bs[128 * 64];
  f32x4 acc[4][4] = {};
  int m0 = blockIdx.y * 128, n0 = blockIdx.x * 128;
  gemm_core(xb, wqkvt, As, Bs, acc, m0, n0);
  int t = threadIdx.x, lane = t & 63, w = t >> 6;
  int lr = lane & 15, lg = lane >> 4;
  int wr = w >> 1, wc = w & 1;
  int which = n0 / DMODEL;
  const float* bias = which == 0 ? bq : (which == 1 ? bk : bv);
  #pragma unroll
  for (int mi = 0; mi < 4; ++mi)
    #pragma unroll
    for (int ni = 0; ni < 4; ++ni)
      #pragma unroll
      for (int r = 0; r < 4; ++r) {
        int srow = m0 + wr * 64 + mi * 16 + lg * 4 + r;
        int col = n0 + wc * 64 + ni * 16 + lr;
        int cc = col - which * DMODEL;
        int h = cc >> 6, e = cc & 63;
        float val = acc[mi][ni][r] + bias[cc];
        if (which < 2) {
          (which ? kd : qd)[h * (SLEN * HD) + srow * HD + e] = (_Float16)val;
        } else {
          vtd[h * (SLEN * HD) + e * SLEN + srow] = (_Float16)val;  // V^T per head
        }
      }
}

// ---------------- flash attention: swapped-operand 32x32x16, 2 waves x 32 q-rows ----------------
__global__ __launch_bounds__(128) void attn_kernel(
    const _Float16* __restrict__ qd, const _Float16* __restrict__ kd,
    const _Float16* __restrict__ vtd, _Float16* __restrict__ attn) {
  __shared__ __align__(16) _Float16 Ks[2][KVBLK * HD];   // [k row][d], XOR-swizzled
  __shared__ __align__(16) _Float16 Vts[2][HD * KVBLK];  // [e row][k], XOR-swizzled
  int wg = blockIdx.x;
  int orig = (wg & 7) * 96 + (wg >> 3);  // bijective XCD swizzle (768 = 8*96)
  int qb = orig & 63, h = orig >> 6;
  int t = threadIdx.x, lane = t & 63, w = t >> 6;
  int ql = lane & 31, hi = lane >> 5;

  const _Float16* kbase = kd + h * (SLEN * HD);
  const _Float16* vbase = vtd + h * (SLEN * HD);

  auto stage = [&](int bi, int jb) {
    #pragma unroll
    for (int i = 0; i < 4; ++i) {
      int c = (w * 4 + i) * 64 + lane;                   // 16B chunk id, 0..511
      int row = c >> 3;
      int sb = ((c & 7) * 16) ^ ((row & 7) << 4);        // inverse-swizzled source bytes
      async16(&Ks[bi][(w * 4 + i) * 512], kbase + (jb * KVBLK + row) * HD + sb / 2);
      async16(&Vts[bi][(w * 4 + i) * 512], vbase + row * SLEN + jb * KVBLK + sb / 2);
    }
  };

  // Q fragments (PV-B-style layout): lane holds q-col ql, d rows hi*8..+8 per 16-chunk
  int qrow = qb * 64 + w * 32 + ql;
  const _Float16* qp = qd + h * (SLEN * HD) + qrow * HD;
  f16x8 qf[4];
  #pragma unroll
  for (int dblk = 0; dblk < 4; ++dblk)
    qf[dblk] = *(const f16x8*)(qp + dblk * 16 + hi * 8);

  f32x16 oacc[2] = {};
  float mrow = -1e30f, lrow = 0.f;
  const float C = 0.18033688f;   // (1/sqrt(64)) * log2(e)
  const float THR = 44.4f;       // 8 / C : defer-max threshold (p <= 2^8)

  stage(0, 0);
  __syncthreads();
  int buf = 0;
  for (int jb = 0; jb < NT; ++jb) {
    if (jb + 1 < NT) stage(buf ^ 1, jb + 1);  // 2-phase prefetch

    // S^T[k][q] = K * Q^T  -> lane owns one q row, k in regs
    f32x16 sacc[2] = {};
    __builtin_amdgcn_s_setprio(1);
    #pragma unroll
    for (int kblk = 0; kblk < 2; ++kblk)
      #pragma unroll
      for (int dblk = 0; dblk < 4; ++dblk) {
        int off = ((kblk * 32 + ql) * 128 + dblk * 32 + hi * 16) ^ ((ql & 7) << 4);
        f16x8 kf = *(const f16x8*)((const char*)Ks[buf] + off);
        sacc[kblk] = __builtin_amdgcn_mfma_f32_32x32x16_f16(kf, qf[dblk], sacc[kblk], 0, 0, 0);
      }
    __builtin_amdgcn_s_setprio(0);

    // in-register online softmax; lane holds 32 of 64 k-values, partner lane^32 the rest
    float mb = sacc[0][0];
    #pragma unroll
    for (int r = 1; r < 16; ++r) mb = fmaxf(mb, sacc[0][r]);
    #pragma unroll
    for (int r = 0; r < 16; ++r) mb = fmaxf(mb, sacc[1][r]);
    {
      unsigned a = __builtin_bit_cast(unsigned, mb), b = a;
      plswap(a, b);
      mb = fmaxf(__builtin_bit_cast(float, a), __builtin_bit_cast(float, b));
    }
    if (!__all(mb <= mrow + THR)) {  // T13 defer-max
      float mn = fmaxf(mrow, mb);
      float corr = __builtin_amdgcn_exp2f((mrow - mn) * C);
      lrow *= corr;
      #pragma unroll
      for (int r = 0; r < 16; ++r) { oacc[0][r] *= corr; oacc[1][r] *= corr; }
      mrow = mn;
    }
    float negm = -mrow * C;
    float p0[16], p1[16], ps = 0.f;
    #pragma unroll
    for (int r = 0; r < 16; ++r) { p0[r] = __builtin_amdgcn_exp2f(fmaf(sacc[0][r], C, negm)); ps += p0[r]; }
    #pragma unroll
    for (int r = 0; r < 16; ++r) { p1[r] = __builtin_amdgcn_exp2f(fmaf(sacc[1][r], C, negm)); ps += p1[r]; }
    lrow += ps;  // partial (own half); partner-combined at epilogue

    // pack P^T B-fragments in-register: 16 cvt_pkrtz + 8 permlane32_swap (T12)
    f16x8 pb[4];
    #pragma unroll
    for (int kblk = 0; kblk < 2; ++kblk) {
      const float* pp = kblk ? p1 : p0;
      #pragma unroll
      for (int u = 0; u < 2; ++u) {
        unsigned a0 = pk(pp[8 * u + 0], pp[8 * u + 1]);
        unsigned b0 = pk(pp[8 * u + 4], pp[8 * u + 5]);
        unsigned a1 = pk(pp[8 * u + 2], pp[8 * u + 3]);
        unsigned b1 = pk(pp[8 * u + 6], pp[8 * u + 7]);
        plswap(a0, b0);
        plswap(a1, b1);
        union { unsigned wd[4]; f16x8 v; } uu;
        uu.wd[0] = a0; uu.wd[1] = a1; uu.wd[2] = b0; uu.wd[3] = b1;
        pb[kblk * 2 + u] = uu.v;
      }
    }

    // O^T[e][q] += V^T * P^T
    __builtin_amdgcn_s_setprio(1);
    #pragma unroll
    for (int kb16 = 0; kb16 < 4; ++kb16)
      #pragma unroll
      for (int eblk = 0; eblk < 2; ++eblk) {
        int off = ((eblk * 32 + ql) * 128 + kb16 * 32 + hi * 16) ^ ((ql & 7) << 4);
        f16x8 vf = *(const f16x8*)((const char*)Vts[buf] + off);
        oacc[eblk] = __builtin_amdgcn_mfma_f32_32x32x16_f16(vf, pb[kb16], oacc[eblk], 0, 0, 0);
      }
    __builtin_amdgcn_s_setprio(0);
    __syncthreads();
    buf ^= 1;
  }

  // epilogue: combine partner row-sum, normalize, store 8B packed (e runs of 4)
  {
    unsigned a = __builtin_bit_cast(unsigned, lrow), b = a;
    plswap(a, b);
    lrow = __builtin_bit_cast(float, a) + __builtin_bit_cast(float, b);
  }
  float inv = 1.f / lrow;
  _Float16* ob = attn + qrow * DMODEL + h * HD;
  #pragma unroll
  for (int eblk = 0; eblk < 2; ++eblk)
    #pragma unroll
    for (int i = 0; i < 4; ++i) {
      unsigned w0 = pk(oacc[eblk][4 * i + 0] * inv, oacc[eblk][4 * i + 1] * inv);
      unsigned w1 = pk(oacc[eblk][4 * i + 2] * inv, oacc[eblk][4 * i + 3] * inv);
      union { unsigned wd[2]; f16x4v v; } uu;
      uu.wd[0] = w0; uu.wd[1] = w1;
      *(f16x4v*)(ob + eblk * 32 + 8 * i + 4 * hi) = uu.v;
    }
}

// ---------------- output projection GEMM ----------------
__global__ __launch_bounds__(256) void gemm_out(
    const _Float16* __restrict__ attn, const _Float16* __restrict__ wot,
    const float* __restrict__ bo, float* __restrict__ out) {
  __shared__ __align__(16) _Float16 As[128 * 64];
  __shared__ __align__(16) _Float16 Bs[128 * 64];
  f32x4 acc[4][4] = {};
  int m0 = blockIdx.y * 128, n0 = blockIdx.x * 128;
  gemm_core(attn, wot, As, Bs, acc, m0, n0);
  int t = threadIdx.x, lane = t & 63, w = t >> 6;
  int lr = lane & 15, lg = lane >> 4;
  int wr = w >> 1, wc = w & 1;
  #pragma unroll
  for (int mi = 0; mi < 4; ++mi)
    #pragma unroll
    for (int ni = 0; ni < 4; ++ni)
      #pragma unroll
      for (int r = 0; r < 4; ++r) {
        int srow = m0 + wr * 64 + mi * 16 + lg * 4 + r;
        int col = n0 + wc * 64 + ni * 16 + lr;
        out[srow * DMODEL + col] = acc[mi][ni][r] + bo[col];
      }
}

extern "C" void kernel_launch(void* const* d_in, const int* in_sizes, int n_in,
                              void* d_out, int out_size, void* d_ws, size_t ws_size,
                              hipStream_t stream) {
  const float* x  = (const float*)d_in[0];
  const float* Wq = (const float*)d_in[1];
  const float* Wk = (const float*)d_in[2];
  const float* Wv = (const float*)d_in[3];
  const float* bq = (const float*)d_in[4];
  const float* bk = (const float*)d_in[5];
  const float* bv = (const float*)d_in[6];
  const float* Wo = (const float*)d_in[7];
  const float* bo = (const float*)d_in[8];
  float* out = (float*)d_out;

  char* ws = (char*)d_ws;
  size_t off = 0;
  auto alloc = [&](size_t bytes) {
    char* p = ws + off;
    off += (bytes + 255) & ~size_t(255);
    return p;
  };
  _Float16* xb    = (_Float16*)alloc((size_t)SLEN * DMODEL * 2);
  _Float16* wqkvt = (_Float16*)alloc((size_t)NQKV * DMODEL * 2);
  _Float16* wot   = (_Float16*)alloc((size_t)DMODEL * DMODEL * 2);
  _Float16* qd    = (_Float16*)alloc((size_t)NH * SLEN * HD * 2);
  _Float16* kd    = (_Float16*)alloc((size_t)NH * SLEN * HD * 2);
  _Float16* vtd   = (_Float16*)alloc((size_t)NH * SLEN * HD * 2);
  _Float16* attn  = (_Float16*)alloc((size_t)SLEN * DMODEL * 2);

  hipLaunchKernelGGL(pack_kernel, dim3(1024), dim3(256), 0, stream,
                     x, Wq, Wk, Wv, Wo, xb, wqkvt, wot);
  hipLaunchKernelGGL(gemm_qkv, dim3(NQKV / 128, SLEN / 128), dim3(256), 0, stream,
                     xb, wqkvt, bq, bk, bv, qd, kd, vtd);
  hipLaunchKernelGGL(attn_kernel, dim3(768), dim3(128), 0, stream,
                     qd, kd, vtd, attn);
  hipLaunchKernelGGL(gemm_out, dim3(DMODEL / 128, SLEN / 128), dim3(256), 0, stream,
                     attn, wot, bo, out);
}

// Round 6
// 242.100 us; speedup vs baseline: 1.3809x; 1.1151x over previous
//
#include <hip/hip_runtime.h>

#define SLEN 4096
#define DMODEL 768
#define NH 12
#define HD 64
#define NQKV 2304
#define KDIM 768
#define KVBLK 64
#define NT (SLEN / KVBLK)

typedef _Float16 f16x8 __attribute__((ext_vector_type(8)));
typedef _Float16 f16x4v __attribute__((ext_vector_type(4)));
typedef float f32x4 __attribute__((ext_vector_type(4)));
typedef float f32x16 __attribute__((ext_vector_type(16)));

__device__ __forceinline__ void async16(void* lds, const void* g) {
  __builtin_amdgcn_global_load_lds((const __attribute__((address_space(1))) void*)g,
                                   (__attribute__((address_space(3))) void*)lds, 16, 0, 0);
}

// permlane32_swap via builtin (SSA-safe; exact half-exchange semantics validated on HW in R5)
__device__ __forceinline__ void plswap(unsigned& a, unsigned& b) {
  auto r = __builtin_amdgcn_permlane32_swap(a, b, false, false);
  a = r[0];
  b = r[1];
}

__device__ __forceinline__ unsigned pk(float a, float b) {
  auto r = __builtin_amdgcn_cvt_pkrtz(a, b);   // __fp16 ext_vector_type(2)
  return __builtin_bit_cast(unsigned, r);
}

// ---------------- pack / convert (vectorized) ----------------
__global__ __launch_bounds__(256) void pack_kernel(
    const float* __restrict__ x, const float* __restrict__ Wq, const float* __restrict__ Wk,
    const float* __restrict__ Wv, const float* __restrict__ Wo,
    _Float16* __restrict__ xb, _Float16* __restrict__ wqkvt, _Float16* __restrict__ wot) {
  int tid = blockIdx.x * 256 + threadIdx.x;
  int stride = gridDim.x * 256;
  int n4 = SLEN * DMODEL / 4;
  for (int i = tid; i < n4; i += stride) {
    float4 v = ((const float4*)x)[i];
    f16x4v o = {(_Float16)v.x, (_Float16)v.y, (_Float16)v.z, (_Float16)v.w};
    ((f16x4v*)xb)[i] = o;
  }
  // wqkvt[col][d], col = which*768 + h*64 + e ; source stride HD floats along d
  n4 = NQKV * DMODEL / 4;
  for (int i = tid; i < n4; i += stride) {
    int col = i / (DMODEL / 4);
    int d = (i - col * (DMODEL / 4)) * 4;
    int which = col / DMODEL;
    int cc = col - which * DMODEL;
    int h = cc >> 6, e = cc & 63;
    const float* W = which == 0 ? Wq : (which == 1 ? Wk : Wv);
    const float* s = W + (h * DMODEL + d) * HD + e;
    f16x4v o = {(_Float16)s[0], (_Float16)s[HD], (_Float16)s[2 * HD], (_Float16)s[3 * HD]};
    ((f16x4v*)wqkvt)[i] = o;
  }
  // wot[o][d] = Wo[d*768+o]
  n4 = DMODEL * DMODEL / 4;
  for (int i = tid; i < n4; i += stride) {
    int o_ = i / (DMODEL / 4);
    int d = (i - o_ * (DMODEL / 4)) * 4;
    const float* s = Wo + d * DMODEL + o_;
    f16x4v o = {(_Float16)s[0], (_Float16)s[DMODEL], (_Float16)s[2 * DMODEL], (_Float16)s[3 * DMODEL]};
    ((f16x4v*)wot)[i] = o;
  }
}

// ---------------- shared GEMM core: C[128,128] = A[128xK] * Bt[128xK]^T ----------------
__device__ __forceinline__ void gemm_core(const _Float16* __restrict__ A,
                                          const _Float16* __restrict__ Bt,
                                          _Float16* As, _Float16* Bs,
                                          f32x4 (&acc)[4][4], int m0, int n0) {
  int t = threadIdx.x;
  int lane = t & 63, w = t >> 6;
  int lr = lane & 15, lg = lane >> 4;
  int wr = w >> 1, wc = w & 1;
  for (int kb = 0; kb < KDIM / 64; ++kb) {
    #pragma unroll
    for (int i = 0; i < 4; ++i) {
      int base = (w * 4 + i) * 512;
      int off = base + lane * 8;
      int row = off >> 6, col = off & 63;
      async16(&As[base], A + (m0 + row) * KDIM + kb * 64 + col);
      async16(&Bs[base], Bt + (n0 + row) * KDIM + kb * 64 + col);
    }
    __syncthreads();
    #pragma unroll
    for (int kk = 0; kk < 2; ++kk) {
      f16x8 af[4], bf[4];
      #pragma unroll
      for (int mi = 0; mi < 4; ++mi)
        af[mi] = *(const f16x8*)&As[(wr * 64 + mi * 16 + lr) * 64 + kk * 32 + lg * 8];
      #pragma unroll
      for (int ni = 0; ni < 4; ++ni)
        bf[ni] = *(const f16x8*)&Bs[(wc * 64 + ni * 16 + lr) * 64 + kk * 32 + lg * 8];
      #pragma unroll
      for (int mi = 0; mi < 4; ++mi)
        #pragma unroll
        for (int ni = 0; ni < 4; ++ni)
          acc[mi][ni] = __builtin_amdgcn_mfma_f32_16x16x32_f16(af[mi], bf[ni], acc[mi][ni], 0, 0, 0);
    }
    __syncthreads();
  }
}

// ---------------- QKV projection GEMM ----------------
__global__ __launch_bounds__(256) void gemm_qkv(
    const _Float16* __restrict__ xb, const _Float16* __restrict__ wqkvt,
    const float* __restrict__ bq, const float* __restrict__ bk, const float* __restrict__ bv,
    _Float16* __restrict__ qd, _Float16* __restrict__ kd, _Float16* __restrict__ vtd) {
  __shared__ __align__(16) _Float16 As[128 * 64];
  __shared__ __align__(16) _Float16 Bs[128 * 64];
  f32x4 acc[4][4] = {};
  int m0 = blockIdx.y * 128, n0 = blockIdx.x * 128;
  gemm_core(xb, wqkvt, As, Bs, acc, m0, n0);
  int t = threadIdx.x, lane = t & 63, w = t >> 6;
  int lr = lane & 15, lg = lane >> 4;
  int wr = w >> 1, wc = w & 1;
  int which = n0 / DMODEL;
  const float* bias = which == 0 ? bq : (which == 1 ? bk : bv);
  #pragma unroll
  for (int mi = 0; mi < 4; ++mi)
    #pragma unroll
    for (int ni = 0; ni < 4; ++ni)
      #pragma unroll
      for (int r = 0; r < 4; ++r) {
        int srow = m0 + wr * 64 + mi * 16 + lg * 4 + r;
        int col = n0 + wc * 64 + ni * 16 + lr;
        int cc = col - which * DMODEL;
        int h = cc >> 6, e = cc & 63;
        float val = acc[mi][ni][r] + bias[cc];
        if (which < 2) {
          (which ? kd : qd)[h * (SLEN * HD) + srow * HD + e] = (_Float16)val;
        } else {
          vtd[h * (SLEN * HD) + e * SLEN + srow] = (_Float16)val;  // V^T per head
        }
      }
}

// ---------------- flash attention: 4 waves = (2 q-halves) x (2 k-halves), 32x32x16 ----------------
__global__ __launch_bounds__(256, 3) void attn_kernel(
    const _Float16* __restrict__ qd, const _Float16* __restrict__ kd,
    const _Float16* __restrict__ vtd, _Float16* __restrict__ attn) {
  __shared__ __align__(16) _Float16 Ks[2][KVBLK * HD];   // [k row][d], XOR-swizzled
  __shared__ __align__(16) _Float16 Vts[2][HD * KVBLK];  // [e row][k], XOR-swizzled
  __shared__ float Om[2][64][32];                        // merge scratch [wq][e][ql]
  __shared__ float Mm[2][32], Lm[2][32];
  int wg = blockIdx.x;
  int orig = (wg & 7) * 96 + (wg >> 3);  // bijective XCD swizzle (768 = 8*96)
  int qb = orig & 63, h = orig >> 6;
  int t = threadIdx.x, lane = t & 63, w = t >> 6;
  int wq = w & 1, wk = w >> 1;
  int ql = lane & 31, hi = lane >> 5;

  const _Float16* kbase = kd + h * (SLEN * HD);
  const _Float16* vbase = vtd + h * (SLEN * HD);

  auto stage = [&](int bi, int jb) {
    #pragma unroll
    for (int i = 0; i < 2; ++i) {
      int c = (w * 2 + i) * 64 + lane;                   // 16B chunk id, 0..511
      int row = c >> 3;
      int sb = ((c & 7) * 16) ^ ((row & 7) << 4);        // inverse-swizzled source bytes
      async16(&Ks[bi][(w * 2 + i) * 512], kbase + (jb * KVBLK + row) * HD + sb / 2);
      async16(&Vts[bi][(w * 2 + i) * 512], vbase + row * SLEN + jb * KVBLK + sb / 2);
    }
  };

  // Q fragments: lane holds q-col ql, d rows hi*8..+8 per 16-chunk
  int qrow = qb * 64 + wq * 32 + ql;
  const _Float16* qp = qd + h * (SLEN * HD) + qrow * HD;
  f16x8 qf[4];
  #pragma unroll
  for (int dblk = 0; dblk < 4; ++dblk)
    qf[dblk] = *(const f16x8*)(qp + dblk * 16 + hi * 8);

  f32x16 oacc[2] = {};
  float mrow = -1e30f, lrow = 0.f;
  const float C = 0.18033688f;   // (1/sqrt(64)) * log2(e)
  const float THR = 44.4f;       // 8 / C : defer-max threshold (p <= 2^8)

  stage(0, 0);
  __syncthreads();
  int buf = 0;
  for (int jb = 0; jb < NT; ++jb) {
    if (jb + 1 < NT) stage(buf ^ 1, jb + 1);  // 2-phase prefetch

    // S^T[k][q] = K * Q^T on this wave's 32-k slice -> lane owns one q row
    f32x16 sacc = {};
    __builtin_amdgcn_s_setprio(1);
    #pragma unroll
    for (int dblk = 0; dblk < 4; ++dblk) {
      int off = ((wk * 32 + ql) * 128 + dblk * 32 + hi * 16) ^ ((ql & 7) << 4);
      f16x8 kf = *(const f16x8*)((const char*)Ks[buf] + off);
      sacc = __builtin_amdgcn_mfma_f32_32x32x16_f16(kf, qf[dblk], sacc, 0, 0, 0);
    }
    __builtin_amdgcn_s_setprio(0);

    // in-register online softmax on 32-k slice; lane holds 16, partner lane^32 the rest
    float mb = sacc[0];
    #pragma unroll
    for (int r = 1; r < 16; ++r) mb = fmaxf(mb, sacc[r]);
    {
      unsigned a = __builtin_bit_cast(unsigned, mb), b = a;
      plswap(a, b);
      mb = fmaxf(__builtin_bit_cast(float, a), __builtin_bit_cast(float, b));
    }
    if (!__all(mb <= mrow + THR)) {  // T13 defer-max
      float mn = fmaxf(mrow, mb);
      float corr = __builtin_amdgcn_exp2f((mrow - mn) * C);
      lrow *= corr;
      #pragma unroll
      for (int r = 0; r < 16; ++r) { oacc[0][r] *= corr; oacc[1][r] *= corr; }
      mrow = mn;
    }
    float negm = -mrow * C;
    float p[16], ps = 0.f;
    #pragma unroll
    for (int r = 0; r < 16; ++r) { p[r] = __builtin_amdgcn_exp2f(fmaf(sacc[r], C, negm)); ps += p[r]; }
    lrow += ps;  // partial (own half); partner-combined at merge

    // pack P^T B-fragments in-register: 8 cvt_pkrtz + 4 permlane32_swap (T12)
    f16x8 pb[2];
    #pragma unroll
    for (int u = 0; u < 2; ++u) {
      unsigned a0 = pk(p[8 * u + 0], p[8 * u + 1]);
      unsigned b0 = pk(p[8 * u + 4], p[8 * u + 5]);
      unsigned a1 = pk(p[8 * u + 2], p[8 * u + 3]);
      unsigned b1 = pk(p[8 * u + 6], p[8 * u + 7]);
      plswap(a0, b0);
      plswap(a1, b1);
      union { unsigned wd[4]; f16x8 v; } uu;
      uu.wd[0] = a0; uu.wd[1] = a1; uu.wd[2] = b0; uu.wd[3] = b1;
      pb[u] = uu.v;
    }

    // O^T[e][q] += V^T * P^T over this wave's 32-k slice
    __builtin_amdgcn_s_setprio(1);
    #pragma unroll
    for (int u = 0; u < 2; ++u)
      #pragma unroll
      for (int eblk = 0; eblk < 2; ++eblk) {
        int off = ((eblk * 32 + ql) * 128 + wk * 64 + u * 32 + hi * 16) ^ ((ql & 7) << 4);
        f16x8 vf = *(const f16x8*)((const char*)Vts[buf] + off);
        oacc[eblk] = __builtin_amdgcn_mfma_f32_32x32x16_f16(vf, pb[u], oacc[eblk], 0, 0, 0);
      }
    __builtin_amdgcn_s_setprio(0);
    __syncthreads();
    buf ^= 1;
  }

  // combine partner (hi-half) row-sum within wave
  {
    unsigned a = __builtin_bit_cast(unsigned, lrow), b = a;
    plswap(a, b);
    lrow = __builtin_bit_cast(float, a) + __builtin_bit_cast(float, b);
  }

  // cross-wave (wk) flash merge through LDS
  if (wk == 1) {
    Mm[wq][ql] = mrow;
    Lm[wq][ql] = lrow;
    #pragma unroll
    for (int eblk = 0; eblk < 2; ++eblk)
      #pragma unroll
      for (int r = 0; r < 16; ++r) {
        int e = eblk * 32 + (r & 3) + 8 * (r >> 2) + 4 * hi;
        Om[wq][e][ql] = oacc[eblk][r];
      }
  }
  __syncthreads();
  if (wk == 0) {
    float m1 = Mm[wq][ql], l1 = Lm[wq][ql];
    float m = fmaxf(mrow, m1);
    float c0 = __builtin_amdgcn_exp2f((mrow - m) * C);
    float c1 = __builtin_amdgcn_exp2f((m1 - m) * C);
    float inv = 1.f / (lrow * c0 + l1 * c1);
    _Float16* ob = attn + qrow * DMODEL + h * HD;
    #pragma unroll
    for (int eblk = 0; eblk < 2; ++eblk) {
      float om[16];
      #pragma unroll
      for (int r = 0; r < 16; ++r) {
        int e = eblk * 32 + (r & 3) + 8 * (r >> 2) + 4 * hi;
        om[r] = (oacc[eblk][r] * c0 + Om[wq][e][ql] * c1) * inv;
      }
      #pragma unroll
      for (int i = 0; i < 4; ++i) {
        unsigned w0 = pk(om[4 * i + 0], om[4 * i + 1]);
        unsigned w1 = pk(om[4 * i + 2], om[4 * i + 3]);
        union { unsigned wd[2]; f16x4v v; } uu;
        uu.wd[0] = w0; uu.wd[1] = w1;
        *(f16x4v*)(ob + eblk * 32 + 8 * i + 4 * hi) = uu.v;
      }
    }
  }
}

// ---------------- output projection GEMM ----------------
__global__ __launch_bounds__(256) void gemm_out(
    const _Float16* __restrict__ attn, const _Float16* __restrict__ wot,
    const float* __restrict__ bo, float* __restrict__ out) {
  __shared__ __align__(16) _Float16 As[128 * 64];
  __shared__ __align__(16) _Float16 Bs[128 * 64];
  f32x4 acc[4][4] = {};
  int m0 = blockIdx.y * 128, n0 = blockIdx.x * 128;
  gemm_core(attn, wot, As, Bs, acc, m0, n0);
  int t = threadIdx.x, lane = t & 63, w = t >> 6;
  int lr = lane & 15, lg = lane >> 4;
  int wr = w >> 1, wc = w & 1;
  #pragma unroll
  for (int mi = 0; mi < 4; ++mi)
    #pragma unroll
    for (int ni = 0; ni < 4; ++ni)
      #pragma unroll
      for (int r = 0; r < 4; ++r) {
        int srow = m0 + wr * 64 + mi * 16 + lg * 4 + r;
        int col = n0 + wc * 64 + ni * 16 + lr;
        out[srow * DMODEL + col] = acc[mi][ni][r] + bo[col];
      }
}

extern "C" void kernel_launch(void* const* d_in, const int* in_sizes, int n_in,
                              void* d_out, int out_size, void* d_ws, size_t ws_size,
                              hipStream_t stream) {
  const float* x  = (const float*)d_in[0];
  const float* Wq = (const float*)d_in[1];
  const float* Wk = (const float*)d_in[2];
  const float* Wv = (const float*)d_in[3];
  const float* bq = (const float*)d_in[4];
  const float* bk = (const float*)d_in[5];
  const float* bv = (const float*)d_in[6];
  const float* Wo = (const float*)d_in[7];
  const float* bo = (const float*)d_in[8];
  float* out = (float*)d_out;

  char* ws = (char*)d_ws;
  size_t off = 0;
  auto alloc = [&](size_t bytes) {
    char* p = ws + off;
    off += (bytes + 255) & ~size_t(255);
    return p;
  };
  _Float16* xb    = (_Float16*)alloc((size_t)SLEN * DMODEL * 2);
  _Float16* wqkvt = (_Float16*)alloc((size_t)NQKV * DMODEL * 2);
  _Float16* wot   = (_Float16*)alloc((size_t)DMODEL * DMODEL * 2);
  _Float16* qd    = (_Float16*)alloc((size_t)NH * SLEN * HD * 2);
  _Float16* kd    = (_Float16*)alloc((size_t)NH * SLEN * HD * 2);
  _Float16* vtd   = (_Float16*)alloc((size_t)NH * SLEN * HD * 2);
  _Float16* attn  = (_Float16*)alloc((size_t)SLEN * DMODEL * 2);

  hipLaunchKernelGGL(pack_kernel, dim3(1024), dim3(256), 0, stream,
                     x, Wq, Wk, Wv, Wo, xb, wqkvt, wot);
  hipLaunchKernelGGL(gemm_qkv, dim3(NQKV / 128, SLEN / 128), dim3(256), 0, stream,
                     xb, wqkvt, bq, bk, bv, qd, kd, vtd);
  hipLaunchKernelGGL(attn_kernel, dim3(768), dim3(256), 0, stream,
                     qd, kd, vtd, attn);
  hipLaunchKernelGGL(gemm_out, dim3(DMODEL / 128, SLEN / 128), dim3(256), 0, stream,
                     attn, wot, bo, out);
}

// Round 8
// 236.951 us; speedup vs baseline: 1.4109x; 1.0217x over previous
//
#include <hip/hip_runtime.h>

#define SLEN 4096
#define DMODEL 768
#define NH 12
#define HD 64
#define NQKV 2304
#define KDIM 768
#define KVBLK 64
#define NT (SLEN / KVBLK)

typedef _Float16 f16x8 __attribute__((ext_vector_type(8)));
typedef _Float16 f16x4v __attribute__((ext_vector_type(4)));
typedef float f32x4 __attribute__((ext_vector_type(4)));
typedef float f32x16 __attribute__((ext_vector_type(16)));

__device__ __forceinline__ void async16(void* lds, const void* g) {
  __builtin_amdgcn_global_load_lds((const __attribute__((address_space(1))) void*)g,
                                   (__attribute__((address_space(3))) void*)lds, 16, 0, 0);
}

// permlane32_swap via builtin (SSA-safe; semantics HW-validated in R5)
__device__ __forceinline__ void plswap(unsigned& a, unsigned& b) {
  auto r = __builtin_amdgcn_permlane32_swap(a, b, false, false);
  a = r[0];
  b = r[1];
}

__device__ __forceinline__ unsigned pk(float a, float b) {
  auto r = __builtin_amdgcn_cvt_pkrtz(a, b);   // __fp16 ext_vector_type(2)
  return __builtin_bit_cast(unsigned, r);
}

// ---------------- pack / convert (vectorized) ----------------
__global__ __launch_bounds__(256) void pack_kernel(
    const float* __restrict__ x, const float* __restrict__ Wq, const float* __restrict__ Wk,
    const float* __restrict__ Wv, const float* __restrict__ Wo,
    _Float16* __restrict__ xb, _Float16* __restrict__ wqkvt, _Float16* __restrict__ wot) {
  int tid = blockIdx.x * 256 + threadIdx.x;
  int stride = gridDim.x * 256;
  int n4 = SLEN * DMODEL / 4;
  for (int i = tid; i < n4; i += stride) {
    float4 v = ((const float4*)x)[i];
    f16x4v o = {(_Float16)v.x, (_Float16)v.y, (_Float16)v.z, (_Float16)v.w};
    ((f16x4v*)xb)[i] = o;
  }
  // wqkvt[col][d], col = which*768 + h*64 + e ; source stride HD floats along d
  n4 = NQKV * DMODEL / 4;
  for (int i = tid; i < n4; i += stride) {
    int col = i / (DMODEL / 4);
    int d = (i - col * (DMODEL / 4)) * 4;
    int which = col / DMODEL;
    int cc = col - which * DMODEL;
    int h = cc >> 6, e = cc & 63;
    const float* W = which == 0 ? Wq : (which == 1 ? Wk : Wv);
    const float* s = W + (h * DMODEL + d) * HD + e;
    f16x4v o = {(_Float16)s[0], (_Float16)s[HD], (_Float16)s[2 * HD], (_Float16)s[3 * HD]};
    ((f16x4v*)wqkvt)[i] = o;
  }
  // wot[o][d] = Wo[d*768+o]
  n4 = DMODEL * DMODEL / 4;
  for (int i = tid; i < n4; i += stride) {
    int o_ = i / (DMODEL / 4);
    int d = (i - o_ * (DMODEL / 4)) * 4;
    const float* s = Wo + d * DMODEL + o_;
    f16x4v o = {(_Float16)s[0], (_Float16)s[DMODEL], (_Float16)s[2 * DMODEL], (_Float16)s[3 * DMODEL]};
    ((f16x4v*)wot)[i] = o;
  }
}

// ---------------- shared GEMM core: C[128,128] = A[128xK] * Bt[128xK]^T ----------------
__device__ __forceinline__ void gemm_core(const _Float16* __restrict__ A,
                                          const _Float16* __restrict__ Bt,
                                          _Float16* As, _Float16* Bs,
                                          f32x4 (&acc)[4][4], int m0, int n0) {
  int t = threadIdx.x;
  int lane = t & 63, w = t >> 6;
  int lr = lane & 15, lg = lane >> 4;
  int wr = w >> 1, wc = w & 1;
  for (int kb = 0; kb < KDIM / 64; ++kb) {
    #pragma unroll
    for (int i = 0; i < 4; ++i) {
      int base = (w * 4 + i) * 512;
      int off = base + lane * 8;
      int row = off >> 6, col = off & 63;
      async16(&As[base], A + (m0 + row) * KDIM + kb * 64 + col);
      async16(&Bs[base], Bt + (n0 + row) * KDIM + kb * 64 + col);
    }
    __syncthreads();
    #pragma unroll
    for (int kk = 0; kk < 2; ++kk) {
      f16x8 af[4], bf[4];
      #pragma unroll
      for (int mi = 0; mi < 4; ++mi)
        af[mi] = *(const f16x8*)&As[(wr * 64 + mi * 16 + lr) * 64 + kk * 32 + lg * 8];
      #pragma unroll
      for (int ni = 0; ni < 4; ++ni)
        bf[ni] = *(const f16x8*)&Bs[(wc * 64 + ni * 16 + lr) * 64 + kk * 32 + lg * 8];
      #pragma unroll
      for (int mi = 0; mi < 4; ++mi)
        #pragma unroll
        for (int ni = 0; ni < 4; ++ni)
          acc[mi][ni] = __builtin_amdgcn_mfma_f32_16x16x32_f16(af[mi], bf[ni], acc[mi][ni], 0, 0, 0);
    }
    __syncthreads();
  }
}

// ---------------- QKV projection GEMM ----------------
__global__ __launch_bounds__(256) void gemm_qkv(
    const _Float16* __restrict__ xb, const _Float16* __restrict__ wqkvt,
    const float* __restrict__ bq, const float* __restrict__ bk, const float* __restrict__ bv,
    _Float16* __restrict__ qd, _Float16* __restrict__ kd, _Float16* __restrict__ vtd) {
  __shared__ __align__(16) _Float16 As[128 * 64];
  __shared__ __align__(16) _Float16 Bs[128 * 64];
  f32x4 acc[4][4] = {};
  int m0 = blockIdx.y * 128, n0 = blockIdx.x * 128;
  gemm_core(xb, wqkvt, As, Bs, acc, m0, n0);
  int t = threadIdx.x, lane = t & 63, w = t >> 6;
  int lr = lane & 15, lg = lane >> 4;
  int wr = w >> 1, wc = w & 1;
  int which = n0 / DMODEL;
  const float* bias = which == 0 ? bq : (which == 1 ? bk : bv);
  #pragma unroll
  for (int mi = 0; mi < 4; ++mi)
    #pragma unroll
    for (int ni = 0; ni < 4; ++ni)
      #pragma unroll
      for (int r = 0; r < 4; ++r) {
        int srow = m0 + wr * 64 + mi * 16 + lg * 4 + r;
        int col = n0 + wc * 64 + ni * 16 + lr;
        int cc = col - which * DMODEL;
        int h = cc >> 6, e = cc & 63;
        float val = acc[mi][ni][r] + bias[cc];
        if (which < 2) {
          (which ? kd : qd)[h * (SLEN * HD) + srow * HD + e] = (_Float16)val;
        } else {
          vtd[h * (SLEN * HD) + e * SLEN + srow] = (_Float16)val;  // V^T per head
        }
      }
}

// ---------------- flash attention: 4 waves = (2 q-halves) x (2 k-halves), 32x32x16 ----------------
// Merge scratch aliased onto dead staging buffers after the K-loop -> 32 KB LDS, 5 blocks/CU.
__global__ __launch_bounds__(256, 5) void attn_kernel(
    const _Float16* __restrict__ qd, const _Float16* __restrict__ kd,
    const _Float16* __restrict__ vtd, _Float16* __restrict__ attn) {
  __shared__ __align__(16) _Float16 Ks[2][KVBLK * HD];   // [k row][d], XOR-swizzled (16 KB)
  __shared__ __align__(16) _Float16 Vts[2][HD * KVBLK];  // [e row][k], XOR-swizzled (16 KB)
  int wg = blockIdx.x;
  int orig = (wg & 7) * 96 + (wg >> 3);  // bijective XCD swizzle (768 = 8*96)
  int qb = orig & 63, h = orig >> 6;
  int t = threadIdx.x, lane = t & 63, w = t >> 6;
  int wq = w & 1, wk = w >> 1;
  int ql = lane & 31, hi = lane >> 5;

  const _Float16* kbase = kd + h * (SLEN * HD);
  const _Float16* vbase = vtd + h * (SLEN * HD);

  auto stage = [&](int bi, int jb) {
    #pragma unroll
    for (int i = 0; i < 2; ++i) {
      int c = (w * 2 + i) * 64 + lane;                   // 16B chunk id, 0..511
      int row = c >> 3;
      int sb = ((c & 7) * 16) ^ ((row & 7) << 4);        // inverse-swizzled source bytes
      async16(&Ks[bi][(w * 2 + i) * 512], kbase + (jb * KVBLK + row) * HD + sb / 2);
      async16(&Vts[bi][(w * 2 + i) * 512], vbase + row * SLEN + jb * KVBLK + sb / 2);
    }
  };

  // Q fragments: lane holds q-col ql, d rows hi*8..+8 per 16-chunk
  int qrow = qb * 64 + wq * 32 + ql;
  const _Float16* qp = qd + h * (SLEN * HD) + qrow * HD;
  f16x8 qf[4];
  #pragma unroll
  for (int dblk = 0; dblk < 4; ++dblk)
    qf[dblk] = *(const f16x8*)(qp + dblk * 16 + hi * 8);

  f32x16 oacc[2] = {};
  float mrow = -1e30f, lrow = 0.f;
  const float C = 0.18033688f;   // (1/sqrt(64)) * log2(e)
  const float THR = 44.4f;       // 8 / C : defer-max threshold (p <= 2^8)

  stage(0, 0);
  __syncthreads();
  int buf = 0;
  for (int jb = 0; jb < NT; ++jb) {
    if (jb + 1 < NT) stage(buf ^ 1, jb + 1);  // 2-phase prefetch

    // S^T[k][q] = K * Q^T on this wave's 32-k slice -> lane owns one q row
    f32x16 sacc = {};
    __builtin_amdgcn_s_setprio(1);
    #pragma unroll
    for (int dblk = 0; dblk < 4; ++dblk) {
      int off = ((wk * 32 + ql) * 128 + dblk * 32 + hi * 16) ^ ((ql & 7) << 4);
      f16x8 kf = *(const f16x8*)((const char*)Ks[buf] + off);
      sacc = __builtin_amdgcn_mfma_f32_32x32x16_f16(kf, qf[dblk], sacc, 0, 0, 0);
    }
    __builtin_amdgcn_s_setprio(0);

    // in-register online softmax on 32-k slice; lane holds 16, partner lane^32 the rest
    float mb = sacc[0];
    #pragma unroll
    for (int r = 1; r < 16; ++r) mb = fmaxf(mb, sacc[r]);
    {
      unsigned a = __builtin_bit_cast(unsigned, mb), b = a;
      plswap(a, b);
      mb = fmaxf(__builtin_bit_cast(float, a), __builtin_bit_cast(float, b));
    }
    if (!__all(mb <= mrow + THR)) {  // T13 defer-max
      float mn = fmaxf(mrow, mb);
      float corr = __builtin_amdgcn_exp2f((mrow - mn) * C);
      lrow *= corr;
      #pragma unroll
      for (int r = 0; r < 16; ++r) { oacc[0][r] *= corr; oacc[1][r] *= corr; }
      mrow = mn;
    }
    float negm = -mrow * C;
    float p[16], ps = 0.f;
    #pragma unroll
    for (int r = 0; r < 16; ++r) { p[r] = __builtin_amdgcn_exp2f(fmaf(sacc[r], C, negm)); ps += p[r]; }
    lrow += ps;  // partial (own half); partner-combined at merge

    // pack P^T B-fragments in-register: 8 cvt_pkrtz + 4 permlane32_swap (T12)
    f16x8 pb[2];
    #pragma unroll
    for (int u = 0; u < 2; ++u) {
      unsigned a0 = pk(p[8 * u + 0], p[8 * u + 1]);
      unsigned b0 = pk(p[8 * u + 4], p[8 * u + 5]);
      unsigned a1 = pk(p[8 * u + 2], p[8 * u + 3]);
      unsigned b1 = pk(p[8 * u + 6], p[8 * u + 7]);
      plswap(a0, b0);
      plswap(a1, b1);
      union { unsigned wd[4]; f16x8 v; } uu;
      uu.wd[0] = a0; uu.wd[1] = a1; uu.wd[2] = b0; uu.wd[3] = b1;
      pb[u] = uu.v;
    }

    // O^T[e][q] += V^T * P^T over this wave's 32-k slice
    __builtin_amdgcn_s_setprio(1);
    #pragma unroll
    for (int u = 0; u < 2; ++u)
      #pragma unroll
      for (int eblk = 0; eblk < 2; ++eblk) {
        int off = ((eblk * 32 + ql) * 128 + wk * 64 + u * 32 + hi * 16) ^ ((ql & 7) << 4);
        f16x8 vf = *(const f16x8*)((const char*)Vts[buf] + off);
        oacc[eblk] = __builtin_amdgcn_mfma_f32_32x32x16_f16(vf, pb[u], oacc[eblk], 0, 0, 0);
      }
    __builtin_amdgcn_s_setprio(0);
    __syncthreads();
    buf ^= 1;
  }

  // combine partner (hi-half) row-sum within wave
  {
    unsigned a = __builtin_bit_cast(unsigned, lrow), b = a;
    plswap(a, b);
    lrow = __builtin_bit_cast(float, a) + __builtin_bit_cast(float, b);
  }

  // cross-wave (wk) flash merge; scratch ALIASES the (now dead) staging buffers.
  float* Om = (float*)&Ks[0][0];        // [2][64][32]  (16 KB, fits in Ks)
  float* Mm = (float*)&Vts[0][0];       // [2][32]
  float* Lm = Mm + 64;                  // [2][32]
  if (wk == 1) {
    Mm[wq * 32 + ql] = mrow;
    Lm[wq * 32 + ql] = lrow;
    #pragma unroll
    for (int eblk = 0; eblk < 2; ++eblk)
      #pragma unroll
      for (int r = 0; r < 16; ++r) {
        int e = eblk * 32 + (r & 3) + 8 * (r >> 2) + 4 * hi;
        Om[(wq * 64 + e) * 32 + ql] = oacc[eblk][r];
      }
  }
  __syncthreads();
  if (wk == 0) {
    float m1 = Mm[wq * 32 + ql], l1 = Lm[wq * 32 + ql];
    float m = fmaxf(mrow, m1);
    float c0 = __builtin_amdgcn_exp2f((mrow - m) * C);
    float c1 = __builtin_amdgcn_exp2f((m1 - m) * C);
    float inv = 1.f / (lrow * c0 + l1 * c1);
    _Float16* ob = attn + qrow * DMODEL + h * HD;
    #pragma unroll
    for (int eblk = 0; eblk < 2; ++eblk) {
      float om[16];
      #pragma unroll
      for (int r = 0; r < 16; ++r) {
        int e = eblk * 32 + (r & 3) + 8 * (r >> 2) + 4 * hi;
        om[r] = (oacc[eblk][r] * c0 + Om[(wq * 64 + e) * 32 + ql] * c1) * inv;
      }
      #pragma unroll
      for (int i = 0; i < 4; ++i) {
        unsigned w0 = pk(om[4 * i + 0], om[4 * i + 1]);
        unsigned w1 = pk(om[4 * i + 2], om[4 * i + 3]);
        union { unsigned wd[2]; f16x4v v; } uu;
        uu.wd[0] = w0; uu.wd[1] = w1;
        *(f16x4v*)(ob + eblk * 32 + 8 * i + 4 * hi) = uu.v;
      }
    }
  }
}

// ---------------- output projection GEMM: 64x64 tiles, 768 blocks (3/CU) ----------------
__global__ __launch_bounds__(256) void gemm_out(
    const _Float16* __restrict__ attn, const _Float16* __restrict__ wot,
    const float* __restrict__ bo, float* __restrict__ out) {
  __shared__ __align__(16) _Float16 As[64 * 64];
  __shared__ __align__(16) _Float16 Bs[64 * 64];
  f32x4 acc[2][2] = {};
  int wg = blockIdx.x;
  int orig = (wg & 7) * 96 + (wg >> 3);  // bijective XCD swizzle (768 = 8*96)
  int mb = orig / 12, nb = orig - mb * 12;
  int m0 = mb * 64, n0 = nb * 64;
  int t = threadIdx.x, lane = t & 63, w = t >> 6;
  int lr = lane & 15, lg = lane >> 4;
  int wr = w >> 1, wc = w & 1;  // 2x2 waves, each 32x32 output
  for (int kb = 0; kb < KDIM / 64; ++kb) {
    #pragma unroll
    for (int i = 0; i < 2; ++i) {
      int base = (w * 2 + i) * 512;
      int off = base + lane * 8;
      int row = off >> 6, col = off & 63;
      async16(&As[base], attn + (m0 + row) * DMODEL + kb * 64 + col);
      async16(&Bs[base], wot + (n0 + row) * DMODEL + kb * 64 + col);
    }
    __syncthreads();
    #pragma unroll
    for (int kk = 0; kk < 2; ++kk) {
      f16x8 af[2], bf[2];
      #pragma unroll
      for (int mi = 0; mi < 2; ++mi)
        af[mi] = *(const f16x8*)&As[(wr * 32 + mi * 16 + lr) * 64 + kk * 32 + lg * 8];
      #pragma unroll
      for (int ni = 0; ni < 2; ++ni)
        bf[ni] = *(const f16x8*)&Bs[(wc * 32 + ni * 16 + lr) * 64 + kk * 32 + lg * 8];
      #pragma unroll
      for (int mi = 0; mi < 2; ++mi)
        #pragma unroll
        for (int ni = 0; ni < 2; ++ni)
          acc[mi][ni] = __builtin_amdgcn_mfma_f32_16x16x32_f16(af[mi], bf[ni], acc[mi][ni], 0, 0, 0);
    }
    __syncthreads();
  }
  #pragma unroll
  for (int mi = 0; mi < 2; ++mi)
    #pragma unroll
    for (int ni = 0; ni < 2; ++ni)
      #pragma unroll
      for (int r = 0; r < 4; ++r) {
        int srow = m0 + wr * 32 + mi * 16 + lg * 4 + r;
        int col = n0 + wc * 32 + ni * 16 + lr;
        out[srow * DMODEL + col] = acc[mi][ni][r] + bo[col];
      }
}

extern "C" void kernel_launch(void* const* d_in, const int* in_sizes, int n_in,
                              void* d_out, int out_size, void* d_ws, size_t ws_size,
                              hipStream_t stream) {
  const float* x  = (const float*)d_in[0];
  const float* Wq = (const float*)d_in[1];
  const float* Wk = (const float*)d_in[2];
  const float* Wv = (const float*)d_in[3];
  const float* bq = (const float*)d_in[4];
  const float* bk = (const float*)d_in[5];
  const float* bv = (const float*)d_in[6];
  const float* Wo = (const float*)d_in[7];
  const float* bo = (const float*)d_in[8];
  float* out = (float*)d_out;

  char* ws = (char*)d_ws;
  size_t off = 0;
  auto alloc = [&](size_t bytes) {
    char* p = ws + off;
    off += (bytes + 255) & ~size_t(255);
    return p;
  };
  _Float16* xb    = (_Float16*)alloc((size_t)SLEN * DMODEL * 2);
  _Float16* wqkvt = (_Float16*)alloc((size_t)NQKV * DMODEL * 2);
  _Float16* wot   = (_Float16*)alloc((size_t)DMODEL * DMODEL * 2);
  _Float16* qd    = (_Float16*)alloc((size_t)NH * SLEN * HD * 2);
  _Float16* kd    = (_Float16*)alloc((size_t)NH * SLEN * HD * 2);
  _Float16* vtd   = (_Float16*)alloc((size_t)NH * SLEN * HD * 2);
  _Float16* attn  = (_Float16*)alloc((size_t)SLEN * DMODEL * 2);

  hipLaunchKernelGGL(pack_kernel, dim3(1024), dim3(256), 0, stream,
                     x, Wq, Wk, Wv, Wo, xb, wqkvt, wot);
  hipLaunchKernelGGL(gemm_qkv, dim3(NQKV / 128, SLEN / 128), dim3(256), 0, stream,
                     xb, wqkvt, bq, bk, bv, qd, kd, vtd);
  hipLaunchKernelGGL(attn_kernel, dim3(768), dim3(256), 0, stream,
                     qd, kd, vtd, attn);
  hipLaunchKernelGGL(gemm_out, dim3(768), dim3(256), 0, stream,
                     attn, wot, bo, out);
}

// Round 9
// 232.880 us; speedup vs baseline: 1.4355x; 1.0175x over previous
//
#include <hip/hip_runtime.h>

#define SLEN 4096
#define DMODEL 768
#define NH 12
#define HD 64
#define NQKV 2304
#define KDIM 768
#define KVBLK 64
#define NT (SLEN / KVBLK)

typedef _Float16 f16x8 __attribute__((ext_vector_type(8)));
typedef _Float16 f16x4v __attribute__((ext_vector_type(4)));
typedef float f32x4 __attribute__((ext_vector_type(4)));
typedef float f32x16 __attribute__((ext_vector_type(16)));

__device__ __forceinline__ void async16(void* lds, const void* g) {
  __builtin_amdgcn_global_load_lds((const __attribute__((address_space(1))) void*)g,
                                   (__attribute__((address_space(3))) void*)lds, 16, 0, 0);
}

// permlane32_swap via builtin (SSA-safe; semantics HW-validated in R5)
__device__ __forceinline__ void plswap(unsigned& a, unsigned& b) {
  auto r = __builtin_amdgcn_permlane32_swap(a, b, false, false);
  a = r[0];
  b = r[1];
}

__device__ __forceinline__ unsigned pk(float a, float b) {
  auto r = __builtin_amdgcn_cvt_pkrtz(a, b);   // __fp16 ext_vector_type(2)
  return __builtin_bit_cast(unsigned, r);
}

// ---------------- pack / convert (vectorized) ----------------
__global__ __launch_bounds__(256) void pack_kernel(
    const float* __restrict__ x, const float* __restrict__ Wq, const float* __restrict__ Wk,
    const float* __restrict__ Wv, const float* __restrict__ Wo,
    _Float16* __restrict__ xb, _Float16* __restrict__ wqkvt, _Float16* __restrict__ wot) {
  int tid = blockIdx.x * 256 + threadIdx.x;
  int stride = gridDim.x * 256;
  int n4 = SLEN * DMODEL / 4;
  for (int i = tid; i < n4; i += stride) {
    float4 v = ((const float4*)x)[i];
    f16x4v o = {(_Float16)v.x, (_Float16)v.y, (_Float16)v.z, (_Float16)v.w};
    ((f16x4v*)xb)[i] = o;
  }
  // wqkvt[col][d], col = which*768 + h*64 + e
  n4 = NQKV * DMODEL / 4;
  for (int i = tid; i < n4; i += stride) {
    int col = i / (DMODEL / 4);
    int d = (i - col * (DMODEL / 4)) * 4;
    int which = col / DMODEL;
    int cc = col - which * DMODEL;
    int h = cc >> 6, e = cc & 63;
    const float* W = which == 0 ? Wq : (which == 1 ? Wk : Wv);
    const float* s = W + (h * DMODEL + d) * HD + e;
    f16x4v o = {(_Float16)s[0], (_Float16)s[HD], (_Float16)s[2 * HD], (_Float16)s[3 * HD]};
    ((f16x4v*)wqkvt)[i] = o;
  }
  // wot[o][d] = Wo[d*768+o]
  n4 = DMODEL * DMODEL / 4;
  for (int i = tid; i < n4; i += stride) {
    int o_ = i / (DMODEL / 4);
    int d = (i - o_ * (DMODEL / 4)) * 4;
    const float* s = Wo + d * DMODEL + o_;
    f16x4v o = {(_Float16)s[0], (_Float16)s[DMODEL], (_Float16)s[2 * DMODEL], (_Float16)s[3 * DMODEL]};
    ((f16x4v*)wot)[i] = o;
  }
}

// ---------------- QKV projection GEMM: 64x128 tiles, 1152 blocks (~4.5/CU) ----------------
__global__ __launch_bounds__(256, 5) void gemm_qkv(
    const _Float16* __restrict__ xb, const _Float16* __restrict__ wqkvt,
    const float* __restrict__ bq, const float* __restrict__ bk, const float* __restrict__ bv,
    _Float16* __restrict__ qd, _Float16* __restrict__ kd, _Float16* __restrict__ vtd) {
  __shared__ __align__(16) _Float16 As[64 * 64];    // 8 KB
  __shared__ __align__(16) _Float16 Bs[128 * 64];   // 16 KB
  int wg = blockIdx.x;
  int orig = (wg & 7) * 144 + (wg >> 3);  // bijective XCD swizzle (1152 = 8*144)
  int nb = orig % 18, mb = orig / 18;
  int m0 = mb * 64, n0 = nb * 128;
  int t = threadIdx.x, lane = t & 63, w = t >> 6;
  int lr = lane & 15, lg = lane >> 4;
  int wc = w;  // each wave owns a 64x32 output panel
  f32x4 acc[4][2] = {};
  for (int kb = 0; kb < KDIM / 64; ++kb) {
    #pragma unroll
    for (int i = 0; i < 2; ++i) {
      int base = (w * 2 + i) * 512;
      int off = base + lane * 8;
      int row = off >> 6, col = off & 63;
      async16(&As[base], xb + (m0 + row) * KDIM + kb * 64 + col);
    }
    #pragma unroll
    for (int i = 0; i < 4; ++i) {
      int base = (w * 4 + i) * 512;
      int off = base + lane * 8;
      int row = off >> 6, col = off & 63;
      async16(&Bs[base], wqkvt + (n0 + row) * KDIM + kb * 64 + col);
    }
    __syncthreads();
    #pragma unroll
    for (int kk = 0; kk < 2; ++kk) {
      f16x8 af[4], bf[2];
      #pragma unroll
      for (int mi = 0; mi < 4; ++mi)
        af[mi] = *(const f16x8*)&As[(mi * 16 + lr) * 64 + kk * 32 + lg * 8];
      #pragma unroll
      for (int ni = 0; ni < 2; ++ni)
        bf[ni] = *(const f16x8*)&Bs[(wc * 32 + ni * 16 + lr) * 64 + kk * 32 + lg * 8];
      #pragma unroll
      for (int mi = 0; mi < 4; ++mi)
        #pragma unroll
        for (int ni = 0; ni < 2; ++ni)
          acc[mi][ni] = __builtin_amdgcn_mfma_f32_16x16x32_f16(af[mi], bf[ni], acc[mi][ni], 0, 0, 0);
    }
    __syncthreads();
  }
  int which = n0 / DMODEL;  // 128-col block never straddles a 768 boundary
  const float* bias = which == 0 ? bq : (which == 1 ? bk : bv);
  #pragma unroll
  for (int mi = 0; mi < 4; ++mi)
    #pragma unroll
    for (int ni = 0; ni < 2; ++ni)
      #pragma unroll
      for (int r = 0; r < 4; ++r) {
        int srow = m0 + mi * 16 + lg * 4 + r;
        int col = n0 + wc * 32 + ni * 16 + lr;
        int cc = col - which * DMODEL;
        int h = cc >> 6, e = cc & 63;
        float val = acc[mi][ni][r] + bias[cc];
        if (which < 2) {
          (which ? kd : qd)[h * (SLEN * HD) + srow * HD + e] = (_Float16)val;
        } else {
          vtd[h * (SLEN * HD) + e * SLEN + srow] = (_Float16)val;  // V^T per head
        }
      }
}

// ---------------- flash attention: KV-split partials + 4 waves (2q x 2k), 32x32x16 ----------------
__global__ __launch_bounds__(256, 5) void attn_kernel(
    const _Float16* __restrict__ qd, const _Float16* __restrict__ kd,
    const _Float16* __restrict__ vtd, _Float16* __restrict__ Op, float* __restrict__ Ml,
    int nsplit, int tilesper) {
  __shared__ __align__(16) _Float16 Ks[2][KVBLK * HD];   // XOR-swizzled (16 KB)
  __shared__ __align__(16) _Float16 Vts[2][HD * KVBLK];  // XOR-swizzled (16 KB)
  int wg = blockIdx.x;
  int nwg = 768 * nsplit;
  int cpx = nwg >> 3;
  int orig = (wg & 7) * cpx + (wg >> 3);  // bijective XCD swizzle
  int s = orig % nsplit, u = orig / nsplit;
  int qb = u & 63, h = u >> 6;
  int t = threadIdx.x, lane = t & 63, w = t >> 6;
  int wq = w & 1, wk = w >> 1;
  int ql = lane & 31, hi = lane >> 5;

  const _Float16* kbase = kd + h * (SLEN * HD);
  const _Float16* vbase = vtd + h * (SLEN * HD);

  auto stage = [&](int bi, int jb) {
    #pragma unroll
    for (int i = 0; i < 2; ++i) {
      int c = (w * 2 + i) * 64 + lane;
      int row = c >> 3;
      int sb = ((c & 7) * 16) ^ ((row & 7) << 4);        // inverse-swizzled source bytes
      async16(&Ks[bi][(w * 2 + i) * 512], kbase + (jb * KVBLK + row) * HD + sb / 2);
      async16(&Vts[bi][(w * 2 + i) * 512], vbase + row * SLEN + jb * KVBLK + sb / 2);
    }
  };

  int qrow = qb * 64 + wq * 32 + ql;
  const _Float16* qp = qd + h * (SLEN * HD) + qrow * HD;
  f16x8 qf[4];
  #pragma unroll
  for (int dblk = 0; dblk < 4; ++dblk)
    qf[dblk] = *(const f16x8*)(qp + dblk * 16 + hi * 8);

  f32x16 oacc[2] = {};
  float mrow = -1e30f, lrow = 0.f;
  const float C = 0.18033688f;   // (1/sqrt(64)) * log2(e)
  const float THR = 44.4f;       // defer-max threshold (p <= 2^8)

  int jb0 = s * tilesper;
  stage(0, jb0);
  __syncthreads();
  int buf = 0;
  for (int jj = 0; jj < tilesper; ++jj) {
    int jb = jb0 + jj;
    if (jj + 1 < tilesper) stage(buf ^ 1, jb + 1);  // 2-phase prefetch

    // S^T[k][q] on this wave's 32-k slice
    f32x16 sacc = {};
    __builtin_amdgcn_s_setprio(1);
    #pragma unroll
    for (int dblk = 0; dblk < 4; ++dblk) {
      int off = ((wk * 32 + ql) * 128 + dblk * 32 + hi * 16) ^ ((ql & 7) << 4);
      f16x8 kf = *(const f16x8*)((const char*)Ks[buf] + off);
      sacc = __builtin_amdgcn_mfma_f32_32x32x16_f16(kf, qf[dblk], sacc, 0, 0, 0);
    }
    __builtin_amdgcn_s_setprio(0);

    // in-register online softmax
    float mb = sacc[0];
    #pragma unroll
    for (int r = 1; r < 16; ++r) mb = fmaxf(mb, sacc[r]);
    {
      unsigned a = __builtin_bit_cast(unsigned, mb), b = a;
      plswap(a, b);
      mb = fmaxf(__builtin_bit_cast(float, a), __builtin_bit_cast(float, b));
    }
    if (!__all(mb <= mrow + THR)) {  // T13 defer-max
      float mn = fmaxf(mrow, mb);
      float corr = __builtin_amdgcn_exp2f((mrow - mn) * C);
      lrow *= corr;
      #pragma unroll
      for (int r = 0; r < 16; ++r) { oacc[0][r] *= corr; oacc[1][r] *= corr; }
      mrow = mn;
    }
    float negm = -mrow * C;
    float p[16], ps = 0.f;
    #pragma unroll
    for (int r = 0; r < 16; ++r) { p[r] = __builtin_amdgcn_exp2f(fmaf(sacc[r], C, negm)); ps += p[r]; }
    lrow += ps;

    // pack P^T B-fragments (T12)
    f16x8 pb[2];
    #pragma unroll
    for (int u2 = 0; u2 < 2; ++u2) {
      unsigned a0 = pk(p[8 * u2 + 0], p[8 * u2 + 1]);
      unsigned b0 = pk(p[8 * u2 + 4], p[8 * u2 + 5]);
      unsigned a1 = pk(p[8 * u2 + 2], p[8 * u2 + 3]);
      unsigned b1 = pk(p[8 * u2 + 6], p[8 * u2 + 7]);
      plswap(a0, b0);
      plswap(a1, b1);
      union { unsigned wd[4]; f16x8 v; } uu;
      uu.wd[0] = a0; uu.wd[1] = a1; uu.wd[2] = b0; uu.wd[3] = b1;
      pb[u2] = uu.v;
    }

    // O^T += V^T * P^T
    __builtin_amdgcn_s_setprio(1);
    #pragma unroll
    for (int u2 = 0; u2 < 2; ++u2)
      #pragma unroll
      for (int eblk = 0; eblk < 2; ++eblk) {
        int off = ((eblk * 32 + ql) * 128 + wk * 64 + u2 * 32 + hi * 16) ^ ((ql & 7) << 4);
        f16x8 vf = *(const f16x8*)((const char*)Vts[buf] + off);
        oacc[eblk] = __builtin_amdgcn_mfma_f32_32x32x16_f16(vf, pb[u2], oacc[eblk], 0, 0, 0);
      }
    __builtin_amdgcn_s_setprio(0);
    __syncthreads();
    buf ^= 1;
  }

  // partner (hi-half) row-sum
  {
    unsigned a = __builtin_bit_cast(unsigned, lrow), b = a;
    plswap(a, b);
    lrow = __builtin_bit_cast(float, a) + __builtin_bit_cast(float, b);
  }

  // cross-wave (wk) flash merge; scratch aliases dead staging buffers
  float* Om = (float*)&Ks[0][0];
  float* Mm = (float*)&Vts[0][0];
  float* Lm = Mm + 64;
  if (wk == 1) {
    Mm[wq * 32 + ql] = mrow;
    Lm[wq * 32 + ql] = lrow;
    #pragma unroll
    for (int eblk = 0; eblk < 2; ++eblk)
      #pragma unroll
      for (int r = 0; r < 16; ++r) {
        int e = eblk * 32 + (r & 3) + 8 * (r >> 2) + 4 * hi;
        Om[(wq * 64 + e) * 32 + ql] = oacc[eblk][r];
      }
  }
  __syncthreads();
  if (wk == 0) {
    float m1 = Mm[wq * 32 + ql], l1 = Lm[wq * 32 + ql];
    float m = fmaxf(mrow, m1);
    float c0 = __builtin_amdgcn_exp2f((mrow - m) * C);
    float c1 = __builtin_amdgcn_exp2f((m1 - m) * C);
    float ltot = lrow * c0 + l1 * c1;
    float inv = 1.f / ltot;
    int q = wq * 32 + ql;
    if (hi == 0) {
      Ml[orig * 128 + q] = m;
      Ml[orig * 128 + 64 + q] = ltot;
    }
    _Float16* ob = Op + (size_t)orig * 4096 + q * 64;  // [q][e], softmax-normalized
    #pragma unroll
    for (int eblk = 0; eblk < 2; ++eblk) {
      float om[16];
      #pragma unroll
      for (int r = 0; r < 16; ++r) {
        int e = eblk * 32 + (r & 3) + 8 * (r >> 2) + 4 * hi;
        om[r] = (oacc[eblk][r] * c0 + Om[(wq * 64 + e) * 32 + ql] * c1) * inv;
      }
      #pragma unroll
      for (int i = 0; i < 4; ++i) {
        unsigned w0 = pk(om[4 * i + 0], om[4 * i + 1]);
        unsigned w1 = pk(om[4 * i + 2], om[4 * i + 3]);
        union { unsigned wd[2]; f16x4v v; } uu;
        uu.wd[0] = w0; uu.wd[1] = w1;
        *(f16x4v*)(ob + eblk * 32 + 8 * i + 4 * hi) = uu.v;
      }
    }
  }
}

// ---------------- merge KV-split partials -> attn f16 buffer ----------------
__global__ __launch_bounds__(256) void merge_kernel(
    const _Float16* __restrict__ Op, const float* __restrict__ Ml,
    _Float16* __restrict__ attn, int nsplit) {
  const float C = 0.18033688f;
  int u = blockIdx.x;           // (h, qb) unit
  int qb = u & 63, h = u >> 6;
  int t = threadIdx.x;
  int e = t & 63, qg = t >> 6;
  for (int j = 0; j < 16; ++j) {
    int q = qg * 16 + j;
    float out;
    if (nsplit == 2) {
      int i0 = u * 2, i1 = u * 2 + 1;
      float m0 = Ml[i0 * 128 + q], l0 = Ml[i0 * 128 + 64 + q];
      float m1 = Ml[i1 * 128 + q], l1 = Ml[i1 * 128 + 64 + q];
      float m = fmaxf(m0, m1);
      float w0 = l0 * __builtin_amdgcn_exp2f((m0 - m) * C);
      float w1 = l1 * __builtin_amdgcn_exp2f((m1 - m) * C);
      float v0 = (float)Op[(size_t)i0 * 4096 + q * 64 + e];
      float v1 = (float)Op[(size_t)i1 * 4096 + q * 64 + e];
      out = (v0 * w0 + v1 * w1) / (w0 + w1);
    } else {
      out = (float)Op[(size_t)u * 4096 + q * 64 + e];
    }
    attn[(size_t)(qb * 64 + q) * DMODEL + h * HD + e] = (_Float16)out;
  }
}

// ---------------- output projection GEMM: 64x64 tiles, 768 blocks (3/CU) ----------------
__global__ __launch_bounds__(256) void gemm_out(
    const _Float16* __restrict__ attn, const _Float16* __restrict__ wot,
    const float* __restrict__ bo, float* __restrict__ out) {
  __shared__ __align__(16) _Float16 As[64 * 64];
  __shared__ __align__(16) _Float16 Bs[64 * 64];
  f32x4 acc[2][2] = {};
  int wg = blockIdx.x;
  int orig = (wg & 7) * 96 + (wg >> 3);  // bijective XCD swizzle (768 = 8*96)
  int mb = orig / 12, nb = orig - mb * 12;
  int m0 = mb * 64, n0 = nb * 64;
  int t = threadIdx.x, lane = t & 63, w = t >> 6;
  int lr = lane & 15, lg = lane >> 4;
  int wr = w >> 1, wc = w & 1;
  for (int kb = 0; kb < KDIM / 64; ++kb) {
    #pragma unroll
    for (int i = 0; i < 2; ++i) {
      int base = (w * 2 + i) * 512;
      int off = base + lane * 8;
      int row = off >> 6, col = off & 63;
      async16(&As[base], attn + (m0 + row) * DMODEL + kb * 64 + col);
      async16(&Bs[base], wot + (n0 + row) * DMODEL + kb * 64 + col);
    }
    __syncthreads();
    #pragma unroll
    for (int kk = 0; kk < 2; ++kk) {
      f16x8 af[2], bf[2];
      #pragma unroll
      for (int mi = 0; mi < 2; ++mi)
        af[mi] = *(const f16x8*)&As[(wr * 32 + mi * 16 + lr) * 64 + kk * 32 + lg * 8];
      #pragma unroll
      for (int ni = 0; ni < 2; ++ni)
        bf[ni] = *(const f16x8*)&Bs[(wc * 32 + ni * 16 + lr) * 64 + kk * 32 + lg * 8];
      #pragma unroll
      for (int mi = 0; mi < 2; ++mi)
        #pragma unroll
        for (int ni = 0; ni < 2; ++ni)
          acc[mi][ni] = __builtin_amdgcn_mfma_f32_16x16x32_f16(af[mi], bf[ni], acc[mi][ni], 0, 0, 0);
    }
    __syncthreads();
  }
  #pragma unroll
  for (int mi = 0; mi < 2; ++mi)
    #pragma unroll
    for (int ni = 0; ni < 2; ++ni)
      #pragma unroll
      for (int r = 0; r < 4; ++r) {
        int srow = m0 + wr * 32 + mi * 16 + lg * 4 + r;
        int col = n0 + wc * 32 + ni * 16 + lr;
        out[srow * DMODEL + col] = acc[mi][ni][r] + bo[col];
      }
}

extern "C" void kernel_launch(void* const* d_in, const int* in_sizes, int n_in,
                              void* d_out, int out_size, void* d_ws, size_t ws_size,
                              hipStream_t stream) {
  const float* x  = (const float*)d_in[0];
  const float* Wq = (const float*)d_in[1];
  const float* Wk = (const float*)d_in[2];
  const float* Wv = (const float*)d_in[3];
  const float* bq = (const float*)d_in[4];
  const float* bk = (const float*)d_in[5];
  const float* bv = (const float*)d_in[6];
  const float* Wo = (const float*)d_in[7];
  const float* bo = (const float*)d_in[8];
  float* out = (float*)d_out;

  char* ws = (char*)d_ws;
  size_t off = 0;
  auto alloc = [&](size_t bytes) {
    char* p = ws + off;
    off += (bytes + 255) & ~size_t(255);
    return p;
  };
  _Float16* xb    = (_Float16*)alloc((size_t)SLEN * DMODEL * 2);
  _Float16* wqkvt = (_Float16*)alloc((size_t)NQKV * DMODEL * 2);
  _Float16* wot   = (_Float16*)alloc((size_t)DMODEL * DMODEL * 2);
  _Float16* qd    = (_Float16*)alloc((size_t)NH * SLEN * HD * 2);
  _Float16* kd    = (_Float16*)alloc((size_t)NH * SLEN * HD * 2);
  _Float16* vtd   = (_Float16*)alloc((size_t)NH * SLEN * HD * 2);
  _Float16* attn  = (_Float16*)alloc((size_t)SLEN * DMODEL * 2);

  // KV-split partial buffers: choose nsplit=2 if workspace permits
  size_t need2 = ((size_t)1536 * 4096 * 2 + 255 + (size_t)1536 * 128 * 4 + 255);
  int nsplit = (ws_size >= off + need2) ? 2 : 1;
  int nunits = 768 * nsplit;
  _Float16* Op = (_Float16*)alloc((size_t)nunits * 4096 * 2);
  float*    Mlb = (float*)alloc((size_t)nunits * 128 * 4);

  hipLaunchKernelGGL(pack_kernel, dim3(1024), dim3(256), 0, stream,
                     x, Wq, Wk, Wv, Wo, xb, wqkvt, wot);
  hipLaunchKernelGGL(gemm_qkv, dim3(1152), dim3(256), 0, stream,
                     xb, wqkvt, bq, bk, bv, qd, kd, vtd);
  hipLaunchKernelGGL(attn_kernel, dim3(nunits), dim3(256), 0, stream,
                     qd, kd, vtd, Op, Mlb, nsplit, NT / nsplit);
  hipLaunchKernelGGL(merge_kernel, dim3(768), dim3(256), 0, stream,
                     Op, Mlb, attn, nsplit);
  hipLaunchKernelGGL(gemm_out, dim3(768), dim3(256), 0, stream,
                     attn, wot, bo, out);
}